// Round 5
// baseline (160.457 us; speedup 1.0000x reference)
//
#include <hip/hip_runtime.h>

#define NEG_SLOPE 0.01f
#define B_ 8
#define N_ 2048
#define F_ 512

typedef unsigned short u16;
typedef __attribute__((ext_vector_type(8))) unsigned short u16x8;
typedef __attribute__((ext_vector_type(8))) _Float16 f16x8;
typedef __attribute__((ext_vector_type(4))) float f32x4;

__device__ __forceinline__ f32x4 mfma16f(u16x8 a, u16x8 b, f32x4 c) {
    return __builtin_amdgcn_mfma_f32_16x16x32_f16(
        __builtin_bit_cast(f16x8, a), __builtin_bit_cast(f16x8, b), c, 0, 0, 0);
}

__device__ __forceinline__ void load_lds16(const void* g, void* l) {
    __builtin_amdgcn_global_load_lds(
        (__attribute__((address_space(1))) void*)(void*)g,
        (__attribute__((address_space(3))) void*)l, 16, 0, 0);
}

// ---- fused prep: Wk -> f16 transposed [N][K]; ws2 = Wk@ws; wn2 = Wk@wn; csn ----
__global__ __launch_bounds__(256) void prep_all(const float* __restrict__ Wk,
                                                const float* __restrict__ bk,
                                                const float* __restrict__ ws,
                                                const float* __restrict__ bs,
                                                const float* __restrict__ wn,
                                                const float* __restrict__ bn,
                                                u16* __restrict__ Wf,
                                                float* __restrict__ ws2,
                                                float* __restrict__ wn2,
                                                float* __restrict__ csn) {
    const int bid = blockIdx.x, t = threadIdx.x;
    if (bid < 1024) {                        // Wk [k][n] -> f16 WfT [n][k]
        const int id = bid * 256 + t;
        const int k = id & 511, n = id >> 9;
        ((_Float16*)Wf)[id] = (_Float16)Wk[k * 512 + n];
        return;
    }
    const int lane = t & 63, w = t >> 6;
    if (bid >= 1280) {                       // csn = {bk.ws+bs, bk.wn+bn}
        if (w == 0) {
            const int sel = bid - 1280;
            const float* vec = sel ? wn : ws;
            const float4 b0 = *(const float4*)(bk + lane * 8);
            const float4 b1 = *(const float4*)(bk + lane * 8 + 4);
            const float4 v0 = *(const float4*)(vec + lane * 8);
            const float4 v1 = *(const float4*)(vec + lane * 8 + 4);
            float d = b0.x * v0.x + b0.y * v0.y + b0.z * v0.z + b0.w * v0.w +
                      b1.x * v1.x + b1.y * v1.y + b1.z * v1.z + b1.w * v1.w;
#pragma unroll
            for (int m = 32; m; m >>= 1) d += __shfl_xor(d, m);
            if (lane == 0) csn[sel] = d + (sel ? bn[0] : bs[0]);
        }
        return;
    }
    const int W = (bid - 1024) * 4 + w;      // 0..1023
    const int k = W & 511;
    const float* vec = (W < 512) ? ws : wn;
    const float4 w0 = *(const float4*)(Wk + (size_t)k * 512 + lane * 8);
    const float4 w1 = *(const float4*)(Wk + (size_t)k * 512 + lane * 8 + 4);
    const float4 v0 = *(const float4*)(vec + lane * 8);
    const float4 v1 = *(const float4*)(vec + lane * 8 + 4);
    float d = w0.x * v0.x + w0.y * v0.y + w0.z * v0.z + w0.w * v0.w +
              w1.x * v1.x + w1.y * v1.y + w1.z * v1.z + w1.w * v1.w;
#pragma unroll
    for (int m = 32; m; m >>= 1) d += __shfl_xor(d, m);
    if (lane == 0) ((W < 512) ? ws2 : wn2)[k] = d;
}

// ---- feat = X @ Wk + bk : single-pass f16 MFMA, XOR-swizzled LDS, f16 out ----
__global__ __launch_bounds__(256) void gemm_feat(const float* __restrict__ X,
                                                 const u16* __restrict__ Wf,
                                                 const float* __restrict__ bk,
                                                 u16* __restrict__ feat) {
    __shared__ u16 Af[128 * 64];
    __shared__ u16 Bf[128 * 64];
    const int t = threadIdx.x;
    const int lane = t & 63;
    const int w = t >> 6;
    const int bid = blockIdx.x;
    const int tm = (bid & 7) * 16 + (bid >> 5);   // XCD swizzle: tn-siblings co-XCD
    const int tn = (bid >> 3) & 3;
    const int wr = w >> 1, wc = w & 1;

    f32x4 acc[4][4];
#pragma unroll
    for (int m = 0; m < 4; ++m)
#pragma unroll
        for (int n = 0; n < 4; ++n) acc[m][n] = {0.f, 0.f, 0.f, 0.f};

    const int lrow = lane >> 3;
    const int scol = ((lane & 7) ^ lrow) * 8;
    const u16* Bbase = Wf + ((size_t)(tn * 128 + w * 8 + lrow)) * 512 + scol;
    u16* BfW = Bf + (w * 8) * 64;

    const int arow = t >> 3;
    const int akk = (t & 7) * 8;
    const float* Abase = X + ((size_t)(tm * 128 + arow)) * 512 + akk;
    u16* AfW = Af + arow * 64 + (akk ^ ((arow & 7) * 8));

    for (int k0 = 0; k0 < 512; k0 += 64) {
#pragma unroll
        for (int iss = 0; iss < 4; ++iss)
            load_lds16(Bbase + (size_t)(iss * 32) * 512 + k0, BfW + iss * 32 * 64);
#pragma unroll
        for (int p = 0; p < 4; ++p) {
            const float4 x0 = *(const float4*)(Abase + (size_t)(p * 32) * 512 + k0);
            const float4 x1 = *(const float4*)(Abase + (size_t)(p * 32) * 512 + k0 + 4);
            const float xv[8] = {x0.x, x0.y, x0.z, x0.w, x1.x, x1.y, x1.z, x1.w};
            u16x8 hv;
#pragma unroll
            for (int e = 0; e < 8; ++e)
                hv[e] = __builtin_bit_cast(u16, (_Float16)xv[e]);
            *(u16x8*)(AfW + p * 32 * 64) = hv;
        }
        __syncthreads();
        const int swz = (lane & 7) * 8;
#pragma unroll
        for (int kk = 0; kk < 64; kk += 32) {
            u16x8 af[4], bf[4];
            const int aoff = (kk + (lane >> 4) * 8) ^ swz;
#pragma unroll
            for (int m = 0; m < 4; ++m)
                af[m] = *(const u16x8*)(Af + (wr * 64 + m * 16 + (lane & 15)) * 64 + aoff);
#pragma unroll
            for (int n = 0; n < 4; ++n)
                bf[n] = *(const u16x8*)(Bf + (wc * 64 + n * 16 + (lane & 15)) * 64 + aoff);
#pragma unroll
            for (int m = 0; m < 4; ++m)
#pragma unroll
                for (int n = 0; n < 4; ++n)
                    acc[m][n] = mfma16f(af[m], bf[n], acc[m][n]);
        }
        __syncthreads();
    }

    const int crow0 = tm * 128 + wr * 64;
    const int ccol0 = tn * 128 + wc * 64;
    _Float16* feat16 = (_Float16*)feat;
#pragma unroll
    for (int n = 0; n < 4; ++n) {
        const int gc = ccol0 + n * 16 + (lane & 15);
        const float bkv = bk[gc];
#pragma unroll
        for (int m = 0; m < 4; ++m) {
            const int gr = crow0 + m * 16 + (lane >> 4) * 4;
#pragma unroll
            for (int r = 0; r < 4; ++r)
                feat16[(size_t)(gr + r) * 512 + gc] = (_Float16)(acc[m][n][r] + bkv);
        }
    }
}

// -------- a_self/a_neigh straight from X (fp32-exact): a = X.ws2 + csn --------
__global__ __launch_bounds__(256) void dots_x(const float* __restrict__ X,
                                              const float* __restrict__ ws2,
                                              const float* __restrict__ wn2,
                                              const float* __restrict__ csn,
                                              float* __restrict__ a_self,
                                              float* __restrict__ a_neigh) {
    const int t = threadIdx.x, lane = t & 63, w = t >> 6;
    const int row = blockIdx.x * 4 + w;
    const float4 f0 = *(const float4*)(X + (size_t)row * 512 + lane * 8);
    const float4 f1 = *(const float4*)(X + (size_t)row * 512 + lane * 8 + 4);
    const float fv[8] = {f0.x, f0.y, f0.z, f0.w, f1.x, f1.y, f1.z, f1.w};
    const float4 sa = *(const float4*)(ws2 + lane * 8);
    const float4 sb = *(const float4*)(ws2 + lane * 8 + 4);
    const float4 na = *(const float4*)(wn2 + lane * 8);
    const float4 nb = *(const float4*)(wn2 + lane * 8 + 4);
    float ds = fv[0] * sa.x + fv[1] * sa.y + fv[2] * sa.z + fv[3] * sa.w +
               fv[4] * sb.x + fv[5] * sb.y + fv[6] * sb.z + fv[7] * sb.w;
    float dn = fv[0] * na.x + fv[1] * na.y + fv[2] * na.z + fv[3] * na.w +
               fv[4] * nb.x + fv[5] * nb.y + fv[6] * nb.z + fv[7] * nb.w;
#pragma unroll
    for (int m = 32; m; m >>= 1) {
        ds += __shfl_xor(ds, m);
        dn += __shfl_xor(dn, m);
    }
    if (lane == 0) {
        a_self[row] = ds + csn[0];
        a_neigh[row] = dn + csn[1];
    }
}

// ---- 1 wave = 1 row: ballot/shfl sparse softmax + f16 gather, no LDS, no barriers ----
__global__ __launch_bounds__(256) void attn_row(const float* __restrict__ A,
                                                const u16* __restrict__ feat,
                                                const float* __restrict__ a_self,
                                                const float* __restrict__ a_neigh,
                                                float* __restrict__ out) {
    const int bid = blockIdx.x;              // 0..4095
    const int t = threadIdx.x;
    const int lane = t & 63, w = t >> 6;
    const int b = bid & 7;                   // XCD b <- batch b (L2 locality)
    const int row = b * N_ + (bid >> 3) * 4 + w;

    const float asi = a_self[row];
    const float4* Arow4 = (const float4*)(A + (size_t)row * N_);
    const float4* An4   = (const float4*)(a_neigh + (size_t)b * N_);

    // entry (c, l, i) -> column c*256 + l*4 + i ; per-lane coalesced float4 loads
    float sv[32];
    unsigned selbits = 0;
    float mloc = -3.0e38f;
#pragma unroll
    for (int c = 0; c < 8; ++c) {
        const float4 a  = Arow4[c * 64 + lane];
        const float4 an = An4[c * 64 + lane];
        const float avi[4] = {a.x, a.y, a.z, a.w};
        const float ani[4] = {an.x, an.y, an.z, an.w};
#pragma unroll
        for (int i = 0; i < 4; ++i) {
            float s = asi * ani[i];
            s = s > 0.f ? s : NEG_SLOPE * s;
            sv[c * 4 + i] = s;
            if (avi[i] != 0.f) {
                selbits |= 1u << (c * 4 + i);
                mloc = fmaxf(mloc, s);
            }
        }
    }
    float mx = mloc;
#pragma unroll
    for (int m = 32; m; m >>= 1) mx = fmaxf(mx, __shfl_xor(mx, m));

    // gather: fixed order (e-major, lane-minor) -> deterministic
    const u16* frow = feat + (size_t)b * N_ * F_ + lane * 8;
    float acc[8] = {0.f, 0.f, 0.f, 0.f, 0.f, 0.f, 0.f, 0.f};
    float ssum = 0.f;
#pragma unroll
    for (int e = 0; e < 32; ++e) {
        unsigned long long mask = __ballot((selbits >> e) & 1u);
        while (mask) {
            const int l = __builtin_ctzll(mask);
            mask &= mask - 1;
            const float s = __shfl(sv[e], l);
            const float p = __expf(s - mx);       // uniform across wave
            const int j = (e >> 2) * 256 + l * 4 + (e & 3);
            const f16x8 vv = *(const f16x8*)(frow + (size_t)j * F_);
#pragma unroll
            for (int i = 0; i < 8; ++i) acc[i] += p * (float)vv[i];
            ssum += p;
        }
    }
    const float inv = 1.f / ssum;

    float o[8];
#pragma unroll
    for (int i = 0; i < 8; ++i) o[i] = tanhf(acc[i] * inv);
    const float4 o0 = {o[0], o[1], o[2], o[3]};
    const float4 o1 = {o[4], o[5], o[6], o[7]};
    float* obase = out + (size_t)row * (8 * F_) + lane * 8;
#pragma unroll
    for (int h = 0; h < 8; ++h) {
        *(float4*)(obase + h * F_)     = o0;
        *(float4*)(obase + h * F_ + 4) = o1;
    }
}

extern "C" void kernel_launch(void* const* d_in, const int* in_sizes, int n_in,
                              void* d_out, int out_size, void* d_ws, size_t ws_size,
                              hipStream_t stream) {
    const float* X  = (const float*)d_in[0];
    const float* A  = (const float*)d_in[1];
    const float* Wk = (const float*)d_in[2];
    const float* bk = (const float*)d_in[3];
    const float* ws = (const float*)d_in[4];
    const float* bs = (const float*)d_in[5];
    const float* wn = (const float*)d_in[6];
    const float* bn = (const float*)d_in[7];
    float* out = (float*)d_out;

    char* wsb = (char*)d_ws;
    u16*   feat    = (u16*)(wsb);                  // 16 MiB (f16)
    u16*   Wf      = (u16*)(wsb + 16777216);       // 0.5 MiB
    float* a_self  = (float*)(wsb + 17301504);     // 64 KiB
    float* a_neigh = (float*)(wsb + 17367040);     // 64 KiB
    float* ws2     = (float*)(wsb + 17432576);     // 2 KiB
    float* wn2     = (float*)(wsb + 17434624);     // 2 KiB
    float* csn     = (float*)(wsb + 17436672);     // 8 B

    prep_all   <<<dim3(1282),  dim3(256), 0, stream>>>(Wk, bk, ws, bs, wn, bn, Wf, ws2, wn2, csn);
    dots_x     <<<dim3(4096),  dim3(256), 0, stream>>>(X, ws2, wn2, csn, a_self, a_neigh);
    gemm_feat  <<<dim3(512),   dim3(256), 0, stream>>>(X, Wf, bk, feat);
    attn_row   <<<dim3(4096),  dim3(256), 0, stream>>>(A, feat, a_self, a_neigh, out);
}

// Round 6
// 155.815 us; speedup vs baseline: 1.0298x; 1.0298x over previous
//
#include <hip/hip_runtime.h>

#define NEG_SLOPE 0.01f
#define B_ 8
#define N_ 2048
#define F_ 512

typedef unsigned short u16;
typedef __attribute__((ext_vector_type(8))) unsigned short u16x8;
typedef __attribute__((ext_vector_type(8))) _Float16 f16x8;
typedef __attribute__((ext_vector_type(4))) float f32x4;

__device__ __forceinline__ f32x4 mfma16f(u16x8 a, u16x8 b, f32x4 c) {
    return __builtin_amdgcn_mfma_f32_16x16x32_f16(
        __builtin_bit_cast(f16x8, a), __builtin_bit_cast(f16x8, b), c, 0, 0, 0);
}

__device__ __forceinline__ void load_lds16(const void* g, void* l) {
    __builtin_amdgcn_global_load_lds(
        (__attribute__((address_space(1))) void*)(void*)g,
        (__attribute__((address_space(3))) void*)l, 16, 0, 0);
}

// ---- fused prep: Wk -> f16 transposed [N][K]; ws2 = Wk@ws; wn2 = Wk@wn; csn ----
__global__ __launch_bounds__(256) void prep_all(const float* __restrict__ Wk,
                                                const float* __restrict__ bk,
                                                const float* __restrict__ ws,
                                                const float* __restrict__ bs,
                                                const float* __restrict__ wn,
                                                const float* __restrict__ bn,
                                                u16* __restrict__ Wf,
                                                float* __restrict__ ws2,
                                                float* __restrict__ wn2,
                                                float* __restrict__ csn) {
    const int bid = blockIdx.x, t = threadIdx.x;
    if (bid < 1024) {                        // Wk [k][n] -> f16 WfT [n][k]
        const int id = bid * 256 + t;
        const int k = id & 511, n = id >> 9;
        ((_Float16*)Wf)[id] = (_Float16)Wk[k * 512 + n];
        return;
    }
    const int lane = t & 63, w = t >> 6;
    if (bid >= 1280) {                       // csn = {bk.ws+bs, bk.wn+bn}
        if (w == 0) {
            const int sel = bid - 1280;
            const float* vec = sel ? wn : ws;
            const float4 b0 = *(const float4*)(bk + lane * 8);
            const float4 b1 = *(const float4*)(bk + lane * 8 + 4);
            const float4 v0 = *(const float4*)(vec + lane * 8);
            const float4 v1 = *(const float4*)(vec + lane * 8 + 4);
            float d = b0.x * v0.x + b0.y * v0.y + b0.z * v0.z + b0.w * v0.w +
                      b1.x * v1.x + b1.y * v1.y + b1.z * v1.z + b1.w * v1.w;
#pragma unroll
            for (int m = 32; m; m >>= 1) d += __shfl_xor(d, m);
            if (lane == 0) csn[sel] = d + (sel ? bn[0] : bs[0]);
        }
        return;
    }
    const int W = (bid - 1024) * 4 + w;      // 0..1023
    const int k = W & 511;
    const float* vec = (W < 512) ? ws : wn;
    const float4 w0 = *(const float4*)(Wk + (size_t)k * 512 + lane * 8);
    const float4 w1 = *(const float4*)(Wk + (size_t)k * 512 + lane * 8 + 4);
    const float4 v0 = *(const float4*)(vec + lane * 8);
    const float4 v1 = *(const float4*)(vec + lane * 8 + 4);
    float d = w0.x * v0.x + w0.y * v0.y + w0.z * v0.z + w0.w * v0.w +
              w1.x * v1.x + w1.y * v1.y + w1.z * v1.z + w1.w * v1.w;
#pragma unroll
    for (int m = 32; m; m >>= 1) d += __shfl_xor(d, m);
    if (lane == 0) ((W < 512) ? ws2 : wn2)[k] = d;
}

// ---- feat = X @ Wk + bk : single-pass f16 MFMA, XOR-swizzled LDS, f16 out ----
__global__ __launch_bounds__(256) void gemm_feat(const float* __restrict__ X,
                                                 const u16* __restrict__ Wf,
                                                 const float* __restrict__ bk,
                                                 u16* __restrict__ feat) {
    __shared__ u16 Af[128 * 64];
    __shared__ u16 Bf[128 * 64];
    const int t = threadIdx.x;
    const int lane = t & 63;
    const int w = t >> 6;
    const int bid = blockIdx.x;
    const int tm = (bid & 7) * 16 + (bid >> 5);   // XCD swizzle: tn-siblings co-XCD
    const int tn = (bid >> 3) & 3;
    const int wr = w >> 1, wc = w & 1;

    f32x4 acc[4][4];
#pragma unroll
    for (int m = 0; m < 4; ++m)
#pragma unroll
        for (int n = 0; n < 4; ++n) acc[m][n] = {0.f, 0.f, 0.f, 0.f};

    const int lrow = lane >> 3;
    const int scol = ((lane & 7) ^ lrow) * 8;
    const u16* Bbase = Wf + ((size_t)(tn * 128 + w * 8 + lrow)) * 512 + scol;
    u16* BfW = Bf + (w * 8) * 64;

    const int arow = t >> 3;
    const int akk = (t & 7) * 8;
    const float* Abase = X + ((size_t)(tm * 128 + arow)) * 512 + akk;
    u16* AfW = Af + arow * 64 + (akk ^ ((arow & 7) * 8));

    for (int k0 = 0; k0 < 512; k0 += 64) {
#pragma unroll
        for (int iss = 0; iss < 4; ++iss)
            load_lds16(Bbase + (size_t)(iss * 32) * 512 + k0, BfW + iss * 32 * 64);
#pragma unroll
        for (int p = 0; p < 4; ++p) {
            const float4 x0 = *(const float4*)(Abase + (size_t)(p * 32) * 512 + k0);
            const float4 x1 = *(const float4*)(Abase + (size_t)(p * 32) * 512 + k0 + 4);
            const float xv[8] = {x0.x, x0.y, x0.z, x0.w, x1.x, x1.y, x1.z, x1.w};
            u16x8 hv;
#pragma unroll
            for (int e = 0; e < 8; ++e)
                hv[e] = __builtin_bit_cast(u16, (_Float16)xv[e]);
            *(u16x8*)(AfW + p * 32 * 64) = hv;
        }
        __syncthreads();
        const int swz = (lane & 7) * 8;
#pragma unroll
        for (int kk = 0; kk < 64; kk += 32) {
            u16x8 af[4], bf[4];
            const int aoff = (kk + (lane >> 4) * 8) ^ swz;
#pragma unroll
            for (int m = 0; m < 4; ++m)
                af[m] = *(const u16x8*)(Af + (wr * 64 + m * 16 + (lane & 15)) * 64 + aoff);
#pragma unroll
            for (int n = 0; n < 4; ++n)
                bf[n] = *(const u16x8*)(Bf + (wc * 64 + n * 16 + (lane & 15)) * 64 + aoff);
#pragma unroll
            for (int m = 0; m < 4; ++m)
#pragma unroll
                for (int n = 0; n < 4; ++n)
                    acc[m][n] = mfma16f(af[m], bf[n], acc[m][n]);
        }
        __syncthreads();
    }

    const int crow0 = tm * 128 + wr * 64;
    const int ccol0 = tn * 128 + wc * 64;
    _Float16* feat16 = (_Float16*)feat;
#pragma unroll
    for (int n = 0; n < 4; ++n) {
        const int gc = ccol0 + n * 16 + (lane & 15);
        const float bkv = bk[gc];
#pragma unroll
        for (int m = 0; m < 4; ++m) {
            const int gr = crow0 + m * 16 + (lane >> 4) * 4;
#pragma unroll
            for (int r = 0; r < 4; ++r)
                feat16[(size_t)(gr + r) * 512 + gc] = (_Float16)(acc[m][n][r] + bkv);
        }
    }
}

// -------- a_self/a_neigh straight from X (fp32-exact): a = X.ws2 + csn --------
__global__ __launch_bounds__(256) void dots_x(const float* __restrict__ X,
                                              const float* __restrict__ ws2,
                                              const float* __restrict__ wn2,
                                              const float* __restrict__ csn,
                                              float* __restrict__ a_self,
                                              float* __restrict__ a_neigh) {
    const int t = threadIdx.x, lane = t & 63, w = t >> 6;
    const int row = blockIdx.x * 4 + w;
    const float4 f0 = *(const float4*)(X + (size_t)row * 512 + lane * 8);
    const float4 f1 = *(const float4*)(X + (size_t)row * 512 + lane * 8 + 4);
    const float fv[8] = {f0.x, f0.y, f0.z, f0.w, f1.x, f1.y, f1.z, f1.w};
    const float4 sa = *(const float4*)(ws2 + lane * 8);
    const float4 sb = *(const float4*)(ws2 + lane * 8 + 4);
    const float4 na = *(const float4*)(wn2 + lane * 8);
    const float4 nb = *(const float4*)(wn2 + lane * 8 + 4);
    float ds = fv[0] * sa.x + fv[1] * sa.y + fv[2] * sa.z + fv[3] * sa.w +
               fv[4] * sb.x + fv[5] * sb.y + fv[6] * sb.z + fv[7] * sb.w;
    float dn = fv[0] * na.x + fv[1] * na.y + fv[2] * na.z + fv[3] * na.w +
               fv[4] * nb.x + fv[5] * nb.y + fv[6] * nb.z + fv[7] * nb.w;
#pragma unroll
    for (int m = 32; m; m >>= 1) {
        ds += __shfl_xor(ds, m);
        dn += __shfl_xor(dn, m);
    }
    if (lane == 0) {
        a_self[row] = ds + csn[0];
        a_neigh[row] = dn + csn[1];
    }
}

// ---- compact_rows: A-row scan -> normalized sparse list (p_hat, j) + count ----
// 1 wave = 1 row. entry (c,l,i) -> col c*256 + l*4 + i.
__global__ __launch_bounds__(256) void compact_rows(const float* __restrict__ A,
                                                    const float* __restrict__ a_self,
                                                    const float* __restrict__ a_neigh,
                                                    float2* __restrict__ list,
                                                    int* __restrict__ cnt_arr) {
    const int bid = blockIdx.x;              // 0..4095
    const int t = threadIdx.x, lane = t & 63, w = t >> 6;
    const int row = bid * 4 + w;
    const int b = row >> 11;

    const float asi = a_self[row];
    const float4* Arow4 = (const float4*)(A + (size_t)row * N_);
    const float4* An4   = (const float4*)(a_neigh + (size_t)b * N_);

    float sv[32];
    unsigned selbits = 0;
    float mloc = -3.0e38f;
#pragma unroll
    for (int c = 0; c < 8; ++c) {
        const float4 a  = Arow4[c * 64 + lane];
        const float4 an = An4[c * 64 + lane];
        const float avi[4] = {a.x, a.y, a.z, a.w};
        const float ani[4] = {an.x, an.y, an.z, an.w};
#pragma unroll
        for (int i = 0; i < 4; ++i) {
            float s = asi * ani[i];
            s = s > 0.f ? s : NEG_SLOPE * s;
            sv[c * 4 + i] = s;
            if (avi[i] != 0.f) {
                selbits |= 1u << (c * 4 + i);
                mloc = fmaxf(mloc, s);
            }
        }
    }
    float mx = mloc;
#pragma unroll
    for (int m = 32; m; m >>= 1) mx = fmaxf(mx, __shfl_xor(mx, m));

    // per-lane exp over own selected entries (~0.64 avg) + local sum
    float lsum = 0.f;
    {
        unsigned mbits = selbits;
        while (mbits) {
            const int e = __builtin_ctz(mbits);
            mbits &= mbits - 1;
            const float p = __expf(sv[e] - mx);
            sv[e] = p;
            lsum += p;
        }
    }
    float tot = lsum;
#pragma unroll
    for (int m = 32; m; m >>= 1) tot += __shfl_xor(tot, m);
    const float inv = 1.f / tot;

    // exclusive scan of per-lane counts -> write positions
    const int cntl = __popc(selbits);
    int v = cntl;
#pragma unroll
    for (int off = 1; off < 64; off <<= 1) {
        const int u = __shfl_up(v, off);
        if (lane >= off) v += u;
    }
    if (lane == 63) cnt_arr[row] = v;
    int pos = v - cntl;

    float2* lr = list + (size_t)row * 128;
    {
        unsigned mbits = selbits;
        while (mbits) {
            const int e = __builtin_ctz(mbits);
            mbits &= mbits - 1;
            const int j = (e >> 2) * 256 + lane * 4 + (e & 3);
            lr[pos] = make_float2(sv[e] * inv, (float)j);
            ++pos;
        }
    }
}

// ---- gather_rows: list held in 2 regs/lane, shfl-broadcast, 4-deep gather ILP ----
__global__ __launch_bounds__(256) void gather_rows(const float2* __restrict__ list,
                                                   const int* __restrict__ cnt_arr,
                                                   const u16* __restrict__ feat,
                                                   float* __restrict__ out) {
    const int bid = blockIdx.x;              // 0..4095
    const int t = threadIdx.x, lane = t & 63, w = t >> 6;
    const int b = bid & 7;                   // XCD b <- batch b (feat L2 locality)
    const int row = b * N_ + (bid >> 3) * 4 + w;

    const int cnt = cnt_arr[row];
    const float2* lr = list + (size_t)row * 128;
    const float2 e0 = lr[lane];
    const float2 e1 = lr[64 + lane];

    const u16* frow = feat + (size_t)b * N_ * F_ + lane * 8;
    float acc[8] = {0.f, 0.f, 0.f, 0.f, 0.f, 0.f, 0.f, 0.f};

    const int c0 = cnt < 64 ? cnt : 64;
    int k = 0;
    for (; k + 4 <= c0; k += 4) {
        const float p0 = __shfl(e0.x, k),     j0 = __shfl(e0.y, k);
        const float p1 = __shfl(e0.x, k + 1), j1 = __shfl(e0.y, k + 1);
        const float p2 = __shfl(e0.x, k + 2), j2 = __shfl(e0.y, k + 2);
        const float p3 = __shfl(e0.x, k + 3), j3 = __shfl(e0.y, k + 3);
        const f16x8 v0 = *(const f16x8*)(frow + (size_t)(int)j0 * F_);
        const f16x8 v1 = *(const f16x8*)(frow + (size_t)(int)j1 * F_);
        const f16x8 v2 = *(const f16x8*)(frow + (size_t)(int)j2 * F_);
        const f16x8 v3 = *(const f16x8*)(frow + (size_t)(int)j3 * F_);
#pragma unroll
        for (int i = 0; i < 8; ++i)
            acc[i] += (p0 * (float)v0[i] + p1 * (float)v1[i]) +
                      (p2 * (float)v2[i] + p3 * (float)v3[i]);
    }
    for (; k < c0; ++k) {
        const float p0 = __shfl(e0.x, k), j0 = __shfl(e0.y, k);
        const f16x8 v0 = *(const f16x8*)(frow + (size_t)(int)j0 * F_);
#pragma unroll
        for (int i = 0; i < 8; ++i) acc[i] += p0 * (float)v0[i];
    }
    for (k = 64; k < cnt; ++k) {             // rare: degree > 64
        const float p0 = __shfl(e1.x, k - 64), j0 = __shfl(e1.y, k - 64);
        const f16x8 v0 = *(const f16x8*)(frow + (size_t)(int)j0 * F_);
#pragma unroll
        for (int i = 0; i < 8; ++i) acc[i] += p0 * (float)v0[i];
    }

    float o[8];
#pragma unroll
    for (int i = 0; i < 8; ++i) o[i] = tanhf(acc[i]);   // p pre-normalized
    const float4 o0 = {o[0], o[1], o[2], o[3]};
    const float4 o1 = {o[4], o[5], o[6], o[7]};
    float* obase = out + (size_t)row * (8 * F_) + lane * 8;
#pragma unroll
    for (int h = 0; h < 8; ++h) {
        *(float4*)(obase + h * F_)     = o0;
        *(float4*)(obase + h * F_ + 4) = o1;
    }
}

extern "C" void kernel_launch(void* const* d_in, const int* in_sizes, int n_in,
                              void* d_out, int out_size, void* d_ws, size_t ws_size,
                              hipStream_t stream) {
    const float* X  = (const float*)d_in[0];
    const float* A  = (const float*)d_in[1];
    const float* Wk = (const float*)d_in[2];
    const float* bk = (const float*)d_in[3];
    const float* ws = (const float*)d_in[4];
    const float* bs = (const float*)d_in[5];
    const float* wn = (const float*)d_in[6];
    const float* bn = (const float*)d_in[7];
    float* out = (float*)d_out;

    char* wsb = (char*)d_ws;
    u16*   feat    = (u16*)(wsb);                  // 16 MiB (f16)
    u16*   Wf      = (u16*)(wsb + 16777216);       // 0.5 MiB
    float* a_self  = (float*)(wsb + 17301504);     // 64 KiB
    float* a_neigh = (float*)(wsb + 17367040);     // 64 KiB
    float* ws2     = (float*)(wsb + 17432576);     // 2 KiB
    float* wn2     = (float*)(wsb + 17434624);     // 2 KiB
    float* csn     = (float*)(wsb + 17436672);     // 8 B
    int*   cnt_arr = (int*)(wsb + 17440768);       // 64 KiB
    float2* list   = (float2*)(wsb + 17825792);    // 16 MiB

    prep_all     <<<dim3(1282), dim3(256), 0, stream>>>(Wk, bk, ws, bs, wn, bn, Wf, ws2, wn2, csn);
    dots_x       <<<dim3(4096), dim3(256), 0, stream>>>(X, ws2, wn2, csn, a_self, a_neigh);
    compact_rows <<<dim3(4096), dim3(256), 0, stream>>>(A, a_self, a_neigh, list, cnt_arr);
    gemm_feat    <<<dim3(512),  dim3(256), 0, stream>>>(X, Wf, bk, feat);
    gather_rows  <<<dim3(4096), dim3(256), 0, stream>>>(list, cnt_arr, feat, out);
}

// Round 8
// 146.493 us; speedup vs baseline: 1.0953x; 1.0636x over previous
//
#include <hip/hip_runtime.h>

#define NEG_SLOPE 0.01f
#define B_ 8
#define N_ 2048
#define F_ 512

typedef unsigned short u16;
typedef __attribute__((ext_vector_type(8))) unsigned short u16x8;
typedef __attribute__((ext_vector_type(8))) _Float16 f16x8;
typedef __attribute__((ext_vector_type(4))) float f32x4;

__device__ __forceinline__ f32x4 mfma16f(u16x8 a, u16x8 b, f32x4 c) {
    return __builtin_amdgcn_mfma_f32_16x16x32_f16(
        __builtin_bit_cast(f16x8, a), __builtin_bit_cast(f16x8, b), c, 0, 0, 0);
}

__device__ __forceinline__ void load_lds16(const void* g, void* l) {
    __builtin_amdgcn_global_load_lds(
        (__attribute__((address_space(1))) void*)(void*)g,
        (__attribute__((address_space(3))) void*)l, 16, 0, 0);
}

// ---- fused prep: Wk -> f16 transposed [N][K]; ws2 = Wk@ws; wn2 = Wk@wn; csn ----
__global__ __launch_bounds__(256) void prep_all(const float* __restrict__ Wk,
                                                const float* __restrict__ bk,
                                                const float* __restrict__ ws,
                                                const float* __restrict__ bs,
                                                const float* __restrict__ wn,
                                                const float* __restrict__ bn,
                                                u16* __restrict__ Wf,
                                                float* __restrict__ ws2,
                                                float* __restrict__ wn2,
                                                float* __restrict__ csn) {
    const int bid = blockIdx.x, t = threadIdx.x;
    if (bid < 1024) {                        // Wk [k][n] -> f16 WfT [n][k]
        const int id = bid * 256 + t;
        const int k = id & 511, n = id >> 9;
        ((_Float16*)Wf)[id] = (_Float16)Wk[k * 512 + n];
        return;
    }
    const int lane = t & 63, w = t >> 6;
    if (bid >= 1280) {                       // csn = {bk.ws+bs, bk.wn+bn}
        if (w == 0) {
            const int sel = bid - 1280;
            const float* vec = sel ? wn : ws;
            const float4 b0 = *(const float4*)(bk + lane * 8);
            const float4 b1 = *(const float4*)(bk + lane * 8 + 4);
            const float4 v0 = *(const float4*)(vec + lane * 8);
            const float4 v1 = *(const float4*)(vec + lane * 8 + 4);
            float d = b0.x * v0.x + b0.y * v0.y + b0.z * v0.z + b0.w * v0.w +
                      b1.x * v1.x + b1.y * v1.y + b1.z * v1.z + b1.w * v1.w;
#pragma unroll
            for (int m = 32; m; m >>= 1) d += __shfl_xor(d, m);
            if (lane == 0) csn[sel] = d + (sel ? bn[0] : bs[0]);
        }
        return;
    }
    const int W = (bid - 1024) * 4 + w;      // 0..1023
    const int k = W & 511;
    const float* vec = (W < 512) ? ws : wn;
    const float4 w0 = *(const float4*)(Wk + (size_t)k * 512 + lane * 8);
    const float4 w1 = *(const float4*)(Wk + (size_t)k * 512 + lane * 8 + 4);
    const float4 v0 = *(const float4*)(vec + lane * 8);
    const float4 v1 = *(const float4*)(vec + lane * 8 + 4);
    float d = w0.x * v0.x + w0.y * v0.y + w0.z * v0.z + w0.w * v0.w +
              w1.x * v1.x + w1.y * v1.y + w1.z * v1.z + w1.w * v1.w;
#pragma unroll
    for (int m = 32; m; m >>= 1) d += __shfl_xor(d, m);
    if (lane == 0) ((W < 512) ? ws2 : wn2)[k] = d;
}

// ---- feat = X @ Wk + bk : single-pass f16 MFMA, XOR-swizzled LDS, f16 out ----
__global__ __launch_bounds__(256) void gemm_feat(const float* __restrict__ X,
                                                 const u16* __restrict__ Wf,
                                                 const float* __restrict__ bk,
                                                 u16* __restrict__ feat) {
    __shared__ u16 Af[128 * 64];
    __shared__ u16 Bf[128 * 64];
    const int t = threadIdx.x;
    const int lane = t & 63;
    const int w = t >> 6;
    const int bid = blockIdx.x;
    const int tm = (bid & 7) * 16 + (bid >> 5);   // XCD swizzle: batch b on XCD b
    const int tn = (bid >> 3) & 3;
    const int wr = w >> 1, wc = w & 1;

    f32x4 acc[4][4];
#pragma unroll
    for (int m = 0; m < 4; ++m)
#pragma unroll
        for (int n = 0; n < 4; ++n) acc[m][n] = {0.f, 0.f, 0.f, 0.f};

    const int lrow = lane >> 3;
    const int scol = ((lane & 7) ^ lrow) * 8;
    const u16* Bbase = Wf + ((size_t)(tn * 128 + w * 8 + lrow)) * 512 + scol;
    u16* BfW = Bf + (w * 8) * 64;

    const int arow = t >> 3;
    const int akk = (t & 7) * 8;
    const float* Abase = X + ((size_t)(tm * 128 + arow)) * 512 + akk;
    u16* AfW = Af + arow * 64 + (akk ^ ((arow & 7) * 8));

    for (int k0 = 0; k0 < 512; k0 += 64) {
#pragma unroll
        for (int iss = 0; iss < 4; ++iss)
            load_lds16(Bbase + (size_t)(iss * 32) * 512 + k0, BfW + iss * 32 * 64);
#pragma unroll
        for (int p = 0; p < 4; ++p) {
            const float4 x0 = *(const float4*)(Abase + (size_t)(p * 32) * 512 + k0);
            const float4 x1 = *(const float4*)(Abase + (size_t)(p * 32) * 512 + k0 + 4);
            const float xv[8] = {x0.x, x0.y, x0.z, x0.w, x1.x, x1.y, x1.z, x1.w};
            u16x8 hv;
#pragma unroll
            for (int e = 0; e < 8; ++e)
                hv[e] = __builtin_bit_cast(u16, (_Float16)xv[e]);
            *(u16x8*)(AfW + p * 32 * 64) = hv;
        }
        __syncthreads();
        const int swz = (lane & 7) * 8;
#pragma unroll
        for (int kk = 0; kk < 64; kk += 32) {
            u16x8 af[4], bf[4];
            const int aoff = (kk + (lane >> 4) * 8) ^ swz;
#pragma unroll
            for (int m = 0; m < 4; ++m)
                af[m] = *(const u16x8*)(Af + (wr * 64 + m * 16 + (lane & 15)) * 64 + aoff);
#pragma unroll
            for (int n = 0; n < 4; ++n)
                bf[n] = *(const u16x8*)(Bf + (wc * 64 + n * 16 + (lane & 15)) * 64 + aoff);
#pragma unroll
            for (int m = 0; m < 4; ++m)
#pragma unroll
                for (int n = 0; n < 4; ++n)
                    acc[m][n] = mfma16f(af[m], bf[n], acc[m][n]);
        }
        __syncthreads();
    }

    const int crow0 = tm * 128 + wr * 64;
    const int ccol0 = tn * 128 + wc * 64;
    _Float16* feat16 = (_Float16*)feat;
#pragma unroll
    for (int n = 0; n < 4; ++n) {
        const int gc = ccol0 + n * 16 + (lane & 15);
        const float bkv = bk[gc];
#pragma unroll
        for (int m = 0; m < 4; ++m) {
            const int gr = crow0 + m * 16 + (lane >> 4) * 4;
#pragma unroll
            for (int r = 0; r < 4; ++r)
                feat16[(size_t)(gr + r) * 512 + gc] = (_Float16)(acc[m][n][r] + bkv);
        }
    }
}

// -------- a_self/a_neigh straight from X (fp32-exact): a = X.ws2 + csn --------
__global__ __launch_bounds__(256) void dots_x(const float* __restrict__ X,
                                              const float* __restrict__ ws2,
                                              const float* __restrict__ wn2,
                                              const float* __restrict__ csn,
                                              float* __restrict__ a_self,
                                              float* __restrict__ a_neigh) {
    const int t = threadIdx.x, lane = t & 63, w = t >> 6;
    const int row = blockIdx.x * 4 + w;
    const float4 f0 = *(const float4*)(X + (size_t)row * 512 + lane * 8);
    const float4 f1 = *(const float4*)(X + (size_t)row * 512 + lane * 8 + 4);
    const float fv[8] = {f0.x, f0.y, f0.z, f0.w, f1.x, f1.y, f1.z, f1.w};
    const float4 sa = *(const float4*)(ws2 + lane * 8);
    const float4 sb = *(const float4*)(ws2 + lane * 8 + 4);
    const float4 na = *(const float4*)(wn2 + lane * 8);
    const float4 nb = *(const float4*)(wn2 + lane * 8 + 4);
    float ds = fv[0] * sa.x + fv[1] * sa.y + fv[2] * sa.z + fv[3] * sa.w +
               fv[4] * sb.x + fv[5] * sb.y + fv[6] * sb.z + fv[7] * sb.w;
    float dn = fv[0] * na.x + fv[1] * na.y + fv[2] * na.z + fv[3] * na.w +
               fv[4] * nb.x + fv[5] * nb.y + fv[6] * nb.z + fv[7] * nb.w;
#pragma unroll
    for (int m = 32; m; m >>= 1) {
        ds += __shfl_xor(ds, m);
        dn += __shfl_xor(dn, m);
    }
    if (lane == 0) {
        a_self[row] = ds + csn[0];
        a_neigh[row] = dn + csn[1];
    }
}

// ---- fused sparse softmax + gather: 1 wave = 1 row ----
// Compaction: 32 unrolled ballot rounds -> wave-private LDS (static reg indexing only).
// Gather: uniform-address LDS broadcasts + 4-deep coalesced f16 row gathers.
// A read nontemporal (streamed once); out write nontemporal (protect feat in L2).
__global__ __launch_bounds__(256) void attn_fused(const float* __restrict__ A,
                                                  const u16* __restrict__ feat,
                                                  const float* __restrict__ a_self,
                                                  const float* __restrict__ a_neigh,
                                                  float* __restrict__ out) {
    __shared__ float2 scratch[4][128];
    const int bid = blockIdx.x;              // 0..4095
    const int t = threadIdx.x, lane = t & 63, w = t >> 6;
    const int b = bid & 7;                   // XCD b <- batch b (feat L2 locality)
    const int row = b * N_ + (bid >> 3) * 4 + w;

    const float asi = a_self[row];
    const f32x4* Arow4 = (const f32x4*)(A + (size_t)row * N_);
    const float4* An4  = (const float4*)(a_neigh + (size_t)b * N_);

    // phase 1: entry (c,l,i) -> col c*256 + l*4 + i ; coalesced nt float4 loads
    float sv[32];
    unsigned selbits = 0;
    float mloc = -3.0e38f;
#pragma unroll
    for (int c = 0; c < 8; ++c) {
        const f32x4 a  = __builtin_nontemporal_load(&Arow4[c * 64 + lane]);
        const float4 an = An4[c * 64 + lane];
        const float avi[4] = {a.x, a.y, a.z, a.w};
        const float ani[4] = {an.x, an.y, an.z, an.w};
#pragma unroll
        for (int i = 0; i < 4; ++i) {
            float s = asi * ani[i];
            s = s > 0.f ? s : NEG_SLOPE * s;
            sv[c * 4 + i] = s;                       // static index
            if (avi[i] != 0.f) {
                selbits |= 1u << (c * 4 + i);
                mloc = fmaxf(mloc, s);
            }
        }
    }
    float mx = mloc;
#pragma unroll
    for (int m = 32; m; m >>= 1) mx = fmaxf(mx, __shfl_xor(mx, m));

    // phase 2: ballot-round compaction into wave-private LDS (order: e-major, lane-minor)
    float2* sc = scratch[w];
    int base = 0;
#pragma unroll
    for (int e = 0; e < 32; ++e) {
        const unsigned long long mask = __ballot((selbits >> e) & 1u);
        if ((selbits >> e) & 1u) {
            const int rank = (int)__popcll(mask & ((1ull << lane) - 1ull));
            const int j = (e >> 2) * 256 + lane * 4 + (e & 3);
            sc[base + rank] = make_float2(sv[e], (float)j);   // sv[e]: static index
        }
        base += (int)__popcll(mask);
    }
    const int cnt = base;                    // wave-uniform
    __syncthreads();                         // LDS visibility (cheap, uniform)

    // phase 3: gather — uniform LDS broadcast of (s,j), exp uniform, 4-deep ILP
    const u16* frow = feat + (size_t)b * N_ * F_ + lane * 8;
    float acc[8] = {0.f, 0.f, 0.f, 0.f, 0.f, 0.f, 0.f, 0.f};
    float ssum = 0.f;
    int k = 0;
    for (; k + 4 <= cnt; k += 4) {
        const float2 E0 = sc[k], E1 = sc[k + 1], E2 = sc[k + 2], E3 = sc[k + 3];
        const float p0 = __expf(E0.x - mx), p1 = __expf(E1.x - mx);
        const float p2 = __expf(E2.x - mx), p3 = __expf(E3.x - mx);
        const f16x8 v0 = *(const f16x8*)(frow + (size_t)(int)E0.y * F_);
        const f16x8 v1 = *(const f16x8*)(frow + (size_t)(int)E1.y * F_);
        const f16x8 v2 = *(const f16x8*)(frow + (size_t)(int)E2.y * F_);
        const f16x8 v3 = *(const f16x8*)(frow + (size_t)(int)E3.y * F_);
        ssum += (p0 + p1) + (p2 + p3);
#pragma unroll
        for (int i = 0; i < 8; ++i)
            acc[i] += (p0 * (float)v0[i] + p1 * (float)v1[i]) +
                      (p2 * (float)v2[i] + p3 * (float)v3[i]);
    }
    for (; k < cnt; ++k) {
        const float2 E0 = sc[k];
        const float p0 = __expf(E0.x - mx);
        const f16x8 v0 = *(const f16x8*)(frow + (size_t)(int)E0.y * F_);
        ssum += p0;
#pragma unroll
        for (int i = 0; i < 8; ++i) acc[i] += p0 * (float)v0[i];
    }
    const float inv = 1.f / ssum;

    float o[8];
#pragma unroll
    for (int i = 0; i < 8; ++i) o[i] = tanhf(acc[i] * inv);
    const f32x4 o0 = {o[0], o[1], o[2], o[3]};
    const f32x4 o1 = {o[4], o[5], o[6], o[7]};
    float* obase = out + (size_t)row * (8 * F_) + lane * 8;
#pragma unroll
    for (int h = 0; h < 8; ++h) {
        __builtin_nontemporal_store(o0, (f32x4*)(obase + h * F_));
        __builtin_nontemporal_store(o1, (f32x4*)(obase + h * F_ + 4));
    }
}

extern "C" void kernel_launch(void* const* d_in, const int* in_sizes, int n_in,
                              void* d_out, int out_size, void* d_ws, size_t ws_size,
                              hipStream_t stream) {
    const float* X  = (const float*)d_in[0];
    const float* A  = (const float*)d_in[1];
    const float* Wk = (const float*)d_in[2];
    const float* bk = (const float*)d_in[3];
    const float* ws = (const float*)d_in[4];
    const float* bs = (const float*)d_in[5];
    const float* wn = (const float*)d_in[6];
    const float* bn = (const float*)d_in[7];
    float* out = (float*)d_out;

    char* wsb = (char*)d_ws;
    u16*   feat    = (u16*)(wsb);                  // 16 MiB (f16)
    u16*   Wf      = (u16*)(wsb + 16777216);       // 0.5 MiB
    float* a_self  = (float*)(wsb + 17301504);     // 64 KiB
    float* a_neigh = (float*)(wsb + 17367040);     // 64 KiB
    float* ws2     = (float*)(wsb + 17432576);     // 2 KiB
    float* wn2     = (float*)(wsb + 17434624);     // 2 KiB
    float* csn     = (float*)(wsb + 17436672);     // 8 B

    prep_all   <<<dim3(1282), dim3(256), 0, stream>>>(Wk, bk, ws, bs, wn, bn, Wf, ws2, wn2, csn);
    dots_x     <<<dim3(4096), dim3(256), 0, stream>>>(X, ws2, wn2, csn, a_self, a_neigh);
    gemm_feat  <<<dim3(512),  dim3(256), 0, stream>>>(X, Wf, bk, feat);
    attn_fused <<<dim3(4096), dim3(256), 0, stream>>>(A, feat, a_self, a_neigh, out);
}